// Round 3
// baseline (5837.647 us; speedup 1.0000x reference)
//
#include <hip/hip_runtime.h>
#include <cstdint>

// ---------------- problem constants ----------------
constexpr int B_ = 4, N_ = 16384, M_ = 2048;
constexpr int COLS0 = B_ * M_ * 32;   // 262144
constexpr int COLS1 = B_ * M_ * 64;   // 524288

// ---------------- workspace layout (bytes), total ~196 MiB (well under 240 MB proven-safe) ----
constexpr size_t OFF_NEWXYZ = 0;                                   // B*3*M fp32
constexpr size_t OFF_NIDX0  = (size_t)B_ * 3 * M_ * 4;             // 98304
constexpr size_t OFF_NIDX1  = OFF_NIDX0 + (size_t)COLS0 * 4;
constexpr size_t OFF_STATS  = OFF_NIDX1 + (size_t)COLS1 * 4;
constexpr size_t STATS_VALS = 64 * 2 * 128;                        // doubles per layer region
constexpr size_t OFF_COEF   = OFF_STATS + 6 * STATS_VALS * 8;      // 6 x 128 float4
constexpr size_t OFF_Z      = OFF_COEF + 6 * 128 * 16;
// Z: per-64-column records [rec][96 ch][64 lanes] fp32; COLS1/64 recs -> 201.3 MB
constexpr int ZSTRIDE = 96 * 64;                                   // floats per record

// ---------------- FPS v4: (x,y) in 128 KiB LDS (guaranteed capacity), z+dd in regs ----------
// R1/R2 post-mortem: the allocator spilled the 64 per-thread point floats to scratch no matter
// what launch bounds said (VGPR=56 both rounds); per-step scratch reload = 256 KB/CU through
// L2 = 1.9 us/step = the whole 4 ms. LDS has EXPLICIT capacity: each thread parks its 16
// points' (x,y) in private LDS slots (no cross-thread reads -> no sync, no conflicts beyond
// the free 2-way), keeps z[16]+dd[16] (~32 regs) in VGPRs -- fits under any budget, spill
// impossible. s_out staging dropped: t0 stores the 6 output words straight to global per step.
// Arithmetic is bit-identical to the passing kernel: same point mapping, same
// (dx*dx+dy*dy)+dz*dz with contract off, same min/argmax order and packed-u64 tie-break.
__global__ __launch_bounds__(1024, 4) void fps_kernel(const float* __restrict__ xyz,
                                                      float* __restrict__ newxyz,
                                                      float* __restrict__ outxyz) {
#pragma clang fp contract(off)
  __shared__ float2 s_xy[N_];                       // 131072 B
  __shared__ unsigned long long s_red[2][16];       // double-buffered per-wave keys
  int b = blockIdx.x, t = threadIdx.x;
  const float* xb = xyz + (size_t)b * 3 * N_;
  float pz[16], dd[16];
#pragma unroll
  for (int i = 0; i < 16; ++i) {
    int n = t + (i << 10);
    float x = xb[n], y = xb[N_ + n];
    pz[i] = xb[2 * N_ + n];
    s_xy[n] = make_float2(x, y);                    // private slot, read back only by this thread
    dd[i] = 1e10f;
    asm volatile("" : "+v"(pz[i]));                 // keep z resident (tiny, always fits)
  }
  size_t base = (size_t)b * 3 * M_;
  float fx = xb[0], fy = xb[N_], fz = xb[2 * N_];
  if (t == 0) {
    newxyz[base] = fx; newxyz[base + M_] = fy; newxyz[base + 2 * M_] = fz;
    outxyz[base] = fx; outxyz[base + M_] = fy; outxyz[base + 2 * M_] = fz;
  }
  int lane = t & 63, wid = t >> 6;
  for (int s = 1; s < M_; ++s) {
    float bv = -1.f; int bi = 0;
#pragma unroll
    for (int i = 0; i < 16; ++i) {
      int n = t + (i << 10);
      float2 xy = s_xy[n];                          // ds_read_b64, own slot
      float dx = xy.x - fx, dy = xy.y - fy, dz = pz[i] - fz;
      float d = (dx * dx + dy * dy) + dz * dz;      // verbatim ref arithmetic (no FMA)
      float dm = dd[i];
      if (d < dm) dm = d;
      dd[i] = dm;
      if (dm > bv) { bv = dm; bi = n; }             // in-thread tie -> smaller n kept
    }
    // key: dist bits (>=0, monotone) high, ~idx low => max key = max dist, tie -> min idx
    unsigned long long key =
        ((unsigned long long)__float_as_uint(bv) << 32) | (unsigned)(0xFFFFFFFFu - (unsigned)bi);
#pragma unroll
    for (int off = 1; off < 64; off <<= 1) {
      unsigned long long o = __shfl_xor(key, off);
      if (o > key) key = o;
    }
    int p = s & 1;
    if (lane == 0) s_red[p][wid] = key;
    __syncthreads();
    // all threads redundantly reduce the 16 wave keys (broadcast LDS reads, short chain)
    unsigned long long k = s_red[p][0];
#pragma unroll
    for (int r = 1; r < 16; ++r) {
      unsigned long long o = s_red[p][r];
      if (o > k) k = o;
    }
    int w = (int)(0xFFFFFFFFu - (unsigned)(k & 0xFFFFFFFFull));
    fx = xb[w]; fy = xb[N_ + w]; fz = xb[2 * N_ + w];   // wave-uniform broadcast load
    if (t == 0) {
      newxyz[base + s] = fx; newxyz[base + M_ + s] = fy; newxyz[base + 2 * M_ + s] = fz;
      outxyz[base + s] = fx; outxyz[base + M_ + s] = fy; outxyz[base + 2 * M_ + s] = fz;
    }
  }
}

// ---------------- ball query: wave per center, ballot-prefix, FMA dot (the proven rounding) ---
template <int KNB>
__global__ __launch_bounds__(256) void bq_kernel(const float* __restrict__ xyz,
                                                 const float* __restrict__ newxyz,
                                                 int* __restrict__ nidx, float r2) {
#pragma clang fp contract(off)
  int t = threadIdx.x, lane = t & 63, wq = t >> 6;
  int q = blockIdx.x * 4 + wq;               // q < B*M
  int b = q >> 11, m = q & 2047;
  const float* xb = xyz + (size_t)b * 3 * N_;
  float cx = newxyz[((size_t)b * 3 + 0) * M_ + m];
  float cy = newxyz[((size_t)b * 3 + 1) * M_ + m];
  float cz = newxyz[((size_t)b * 3 + 2) * M_ + m];
  float sqc = (cx * cx + cy * cy) + cz * cz;         // no fma
  int found = 0, first = 0;
  for (int c = 0; c < N_ / 64; ++c) {
    int n = c * 64 + lane;
    float x = xb[n], y = xb[N_ + n], z = xb[2 * N_ + n];
    float sqx = (x * x + y * y) + z * z;             // no fma
    float dot = fmaf(cz, z, fmaf(cy, y, cx * x));    // fma chain (proven ref rounding, R10)
    float d2 = (sqc + sqx) - 2.0f * dot;
    bool in = d2 < r2;
    unsigned long long mask = __ballot(in);
    if (mask) {
      if (found == 0) first = c * 64 + (__ffsll((long long)mask) - 1);
      int pos = found + __popcll(mask & ((1ull << lane) - 1ull));
      if (in && pos < KNB) nidx[(size_t)q * KNB + pos] = n;
      found += __popcll(mask);
      if (found >= KNB) break;                       // first K ascending == K smallest indices
    }
  }
  if (found < KNB) {
    int fill = (found == 0) ? 0 : first;
    for (int s = found + lane; s < KNB; s += 64) nidx[(size_t)q * KNB + s] = fill;
  }
}

// ---------------- per-channel stats: fp32 butterfly partials -> f64 bucketed atomics ----------
__device__ __forceinline__ void stat_accum(float acc, int o, int cout, double* stats,
                                           int part, int lane) {
  float v1 = acc, v2 = acc * acc;
#pragma unroll
  for (int off = 1; off < 64; off <<= 1) {
    v1 += __shfl_xor(v1, off);
    v2 += __shfl_xor(v2, off);
  }
  if (lane == 0) {
    atomicAdd(stats + ((size_t)part * 2 + 0) * cout + o, (double)v1);
    atomicAdd(stats + ((size_t)part * 2 + 1) * cout + o, (double)v2);
  }
}

// ---------------- layer 0: gather -> conv(67->64) -> record store + stats ---------------------
template <int KNB>
__global__ __launch_bounds__(256) void convL0_kernel(
    const float* __restrict__ w0,              // [64][67] raw
    const float* __restrict__ xyz, const float* __restrict__ feat,
    const int* __restrict__ nidx, const float* __restrict__ newxyz,
    float* __restrict__ Z, double* __restrict__ stats) {
  int lane = threadIdx.x & 63, wq = threadIdx.x >> 6;
  int rec = blockIdx.x * 4 + wq;
  int col = rec * 64 + lane;
  float x[67];
  {
    int b = col / (M_ * KNB);
    int rem = col - b * (M_ * KNB);
    int m = rem / KNB;
    int n = nidx[col];
    const float* xb = xyz + (size_t)b * 3 * N_;
    x[0] = xb[n]          - newxyz[((size_t)b * 3 + 0) * M_ + m];
    x[1] = xb[N_ + n]     - newxyz[((size_t)b * 3 + 1) * M_ + m];
    x[2] = xb[2 * N_ + n] - newxyz[((size_t)b * 3 + 2) * M_ + m];
    const float* fb = feat + (size_t)b * 64 * N_;
#pragma unroll
    for (int c = 0; c < 64; ++c) x[3 + c] = fb[(size_t)c * N_ + n];   // L2/L3-resident
  }
  float* zr = Z + (size_t)rec * ZSTRIDE;
  int part = rec & 63;
  for (int o = 0; o < 64; ++o) {
    const float* wr = w0 + (size_t)o * 67;     // wave-uniform -> scalar loads
    float acc = 0.f;
#pragma unroll
    for (int c = 0; c < 67; ++c) acc += wr[c] * x[c];
    zr[o * 64 + lane] = acc;                   // coalesced 256B row store
    stat_accum(acc, o, 64, stats, part, lane);
  }
}

// ---------------- mid layer: record load + BN-apply -> conv -> in-place store + stats ---------
template <int CIN, int COUT>
__global__ __launch_bounds__(256) void convMid_kernel(
    const float* __restrict__ w,               // [COUT][CIN] raw
    const float4* __restrict__ coefIn,         // prev layer (mu, rstd, g, b)
    float* __restrict__ Z, double* __restrict__ stats) {
  int lane = threadIdx.x & 63, wq = threadIdx.x >> 6;
  int rec = blockIdx.x * 4 + wq;
  float* zr = Z + (size_t)rec * ZSTRIDE;
  float x[CIN];
#pragma unroll
  for (int c = 0; c < CIN; ++c) {              // load all to regs, then safe in-place overwrite
    float v = zr[c * 64 + lane];
    float4 cf = coefIn[c];
    x[c] = fmaxf(((v - cf.x) * cf.y) * cf.z + cf.w, 0.f);   // ref op order
  }
  int part = rec & 63;
  for (int o = 0; o < COUT; ++o) {
    const float* wr = w + (size_t)o * CIN;
    float acc = 0.f;
#pragma unroll
    for (int c = 0; c < CIN; ++c) acc += wr[c] * x[c];
    zr[o * 64 + lane] = acc;
    stat_accum(acc, o, COUT, stats, part, lane);
  }
}

// ---------------- last layer, pass A: stats only (conv result discarded) ----------------------
template <int CIN>
__global__ __launch_bounds__(256) void convLastStats_kernel(
    const float* __restrict__ w, const float4* __restrict__ coefIn,
    const float* __restrict__ Z, double* __restrict__ stats) {
  int lane = threadIdx.x & 63, wq = threadIdx.x >> 6;
  int rec = blockIdx.x * 4 + wq;
  const float* zr = Z + (size_t)rec * ZSTRIDE;
  float x[CIN];
#pragma unroll
  for (int c = 0; c < CIN; ++c) {
    float v = zr[c * 64 + lane];
    float4 cf = coefIn[c];
    x[c] = fmaxf(((v - cf.x) * cf.y) * cf.z + cf.w, 0.f);
  }
  int part = rec & 63;
  for (int o = 0; o < 128; ++o) {
    const float* wr = w + (size_t)o * CIN;
    float acc = 0.f;
#pragma unroll
    for (int c = 0; c < CIN; ++c) acc += wr[c] * x[c];
    stat_accum(acc, o, 128, stats, part, lane);
  }
}

// ---------------- last layer, pass B: recompute conv + BN + ReLU + max over K + write out -----
template <int CIN, int KNB>
__global__ __launch_bounds__(256) void convLastPool_kernel(
    const float* __restrict__ w, const float4* __restrict__ coefIn,
    const float4* __restrict__ coefOut,
    const float* __restrict__ Z, float* __restrict__ outFeats, int chBase) {
  int lane = threadIdx.x & 63, wq = threadIdx.x >> 6;
  int rec = blockIdx.x * 4 + wq;
  const float* zr = Z + (size_t)rec * ZSTRIDE;
  float x[CIN];
#pragma unroll
  for (int c = 0; c < CIN; ++c) {
    float v = zr[c * 64 + lane];
    float4 cf = coefIn[c];
    x[c] = fmaxf(((v - cf.x) * cf.y) * cf.z + cf.w, 0.f);
  }
  for (int o = 0; o < 128; ++o) {
    const float* wr = w + (size_t)o * CIN;
    float acc = 0.f;
#pragma unroll
    for (int c = 0; c < CIN; ++c) acc += wr[c] * x[c];
    float4 cf = coefOut[o];
    float z = fmaxf(((acc - cf.x) * cf.y) * cf.z + cf.w, 0.f);
    if (KNB == 64) {
#pragma unroll
      for (int off = 1; off < 64; off <<= 1) z = fmaxf(z, __shfl_xor(z, off));
      if (lane == 0) {
        int b = rec >> 11, m = rec & 2047;
        outFeats[((size_t)b * 256 + chBase + o) * M_ + m] = z;
      }
    } else {                                    // KNB == 32: two groups per wave
#pragma unroll
      for (int off = 1; off < 32; off <<= 1) z = fmaxf(z, __shfl_xor(z, off));
      if ((lane & 31) == 0) {
        int grp = rec * 2 + (lane >> 5);
        int b = grp >> 11, m = grp & 2047;
        outFeats[((size_t)b * 256 + chBase + o) * M_ + m] = z;
      }
    }
  }
}

// ---------------- fold fp64 BN stats into per-channel (mu, rstd, g, b) ----------------
__global__ void coef_kernel(const double* __restrict__ stats, const float* __restrict__ g,
                            const float* __restrict__ bb, float4* __restrict__ coef,
                            int cout, double invcnt) {
  int ch = threadIdx.x;
  if (ch >= cout) return;
  double s1 = 0.0, s2 = 0.0;
  for (int p = 0; p < 64; ++p) {
    s1 += stats[((size_t)p * 2 + 0) * cout + ch];
    s2 += stats[((size_t)p * 2 + 1) * cout + ch];
  }
  double mean = s1 * invcnt;
  double var = s2 * invcnt - mean * mean;
  double rstd = 1.0 / sqrt(var + 1e-5);
  coef[ch] = make_float4((float)mean, (float)rstd, g[ch], bb[ch]);
}

// ---------------- launcher ----------------
extern "C" void kernel_launch(void* const* d_in, const int* in_sizes, int n_in,
                              void* d_out, int out_size, void* d_ws, size_t ws_size,
                              hipStream_t stream) {
  const float* xyz  = (const float*)d_in[0];
  const float* feat = (const float*)d_in[1];
  const float* w00 = (const float*)d_in[2],  *g00 = (const float*)d_in[3],  *b00 = (const float*)d_in[4];
  const float* w01 = (const float*)d_in[5],  *g01 = (const float*)d_in[6],  *b01 = (const float*)d_in[7];
  const float* w02 = (const float*)d_in[8],  *g02 = (const float*)d_in[9],  *b02 = (const float*)d_in[10];
  const float* w10 = (const float*)d_in[11], *g10 = (const float*)d_in[12], *b10 = (const float*)d_in[13];
  const float* w11 = (const float*)d_in[14], *g11 = (const float*)d_in[15], *b11 = (const float*)d_in[16];
  const float* w12 = (const float*)d_in[17], *g12 = (const float*)d_in[18], *b12 = (const float*)d_in[19];

  char* ws = (char*)d_ws;
  float*  newxyz = (float*)(ws + OFF_NEWXYZ);
  int*    nidx0  = (int*)(ws + OFF_NIDX0);
  int*    nidx1  = (int*)(ws + OFF_NIDX1);
  double* stats  = (double*)(ws + OFF_STATS);
  float4* coef   = (float4*)(ws + OFF_COEF);
  float*  Z      = (float*)(ws + OFF_Z);
  float* outF = (float*)d_out;
  float* outFeats = outF + (size_t)B_ * 3 * M_;

  hipMemsetAsync(ws + OFF_STATS, 0, 6 * STATS_VALS * 8, stream);
  fps_kernel<<<B_, 1024, 0, stream>>>(xyz, newxyz, outF);
  bq_kernel<32><<<(B_ * M_) / 4, 256, 0, stream>>>(xyz, newxyz, nidx0, (float)(0.2 * 0.2));
  bq_kernel<64><<<(B_ * M_) / 4, 256, 0, stream>>>(xyz, newxyz, nidx1, (float)(0.4 * 0.4));

  float4* c00 = coef + 0 * 128; float4* c01 = coef + 1 * 128; float4* c02 = coef + 2 * 128;
  float4* c10 = coef + 3 * 128; float4* c11 = coef + 4 * 128; float4* c12 = coef + 5 * 128;
  double* st0 = stats + 0 * STATS_VALS; double* st1 = stats + 1 * STATS_VALS;
  double* st2 = stats + 2 * STATS_VALS; double* st3 = stats + 3 * STATS_VALS;
  double* st4 = stats + 4 * STATS_VALS; double* st5 = stats + 5 * STATS_VALS;
  int gb0 = (COLS0 / 64) / 4, gb1 = (COLS1 / 64) / 4;   // 4 records per 256-thr block

  // ---- scale 0 (K=32): 67->64->64->128 ----
  convL0_kernel<32><<<gb0, 256, 0, stream>>>(w00, xyz, feat, nidx0, newxyz, Z, st0);
  coef_kernel<<<1, 128, 0, stream>>>(st0, g00, b00, c00, 64, 1.0 / COLS0);
  convMid_kernel<64, 64><<<gb0, 256, 0, stream>>>(w01, c00, Z, st1);
  coef_kernel<<<1, 128, 0, stream>>>(st1, g01, b01, c01, 64, 1.0 / COLS0);
  convLastStats_kernel<64><<<gb0, 256, 0, stream>>>(w02, c01, Z, st2);
  coef_kernel<<<1, 128, 0, stream>>>(st2, g02, b02, c02, 128, 1.0 / COLS0);
  convLastPool_kernel<64, 32><<<gb0, 256, 0, stream>>>(w02, c01, c02, Z, outFeats, 0);

  // ---- scale 1 (K=64): 67->64->96->128 ----
  convL0_kernel<64><<<gb1, 256, 0, stream>>>(w10, xyz, feat, nidx1, newxyz, Z, st3);
  coef_kernel<<<1, 128, 0, stream>>>(st3, g10, b10, c10, 64, 1.0 / COLS1);
  convMid_kernel<64, 96><<<gb1, 256, 0, stream>>>(w11, c10, Z, st4);
  coef_kernel<<<1, 128, 0, stream>>>(st4, g11, b11, c11, 96, 1.0 / COLS1);
  convLastStats_kernel<96><<<gb1, 256, 0, stream>>>(w12, c11, Z, st5);
  coef_kernel<<<1, 128, 0, stream>>>(st5, g12, b12, c12, 128, 1.0 / COLS1);
  convLastPool_kernel<96, 64><<<gb1, 256, 0, stream>>>(w12, c11, c12, Z, outFeats, 128);
}

// Round 4
// 5195.621 us; speedup vs baseline: 1.1236x; 1.1236x over previous
//
#include <hip/hip_runtime.h>
#include <cstdint>

// ---------------- problem constants ----------------
constexpr int B_ = 4, N_ = 16384, M_ = 2048;
constexpr int COLS0 = B_ * M_ * 32;   // 262144
constexpr int COLS1 = B_ * M_ * 64;   // 524288

// ---------------- FPS partitioning ----------------
constexpr int FPS_G   = 8;                       // blocks per batch (8 CUs cooperate)
constexpr int FPS_T   = 512;                     // threads per fps block
constexpr int FPS_PPT = N_ / FPS_G / FPS_T;      // 4 points per thread (pure registers)

// ---------------- workspace layout (bytes), total ~210 MiB (under 240 MB proven-safe) --------
constexpr size_t OFF_NEWXYZ = 0;                                   // B*3*M fp32
constexpr size_t OFF_NIDX0  = (size_t)B_ * 3 * M_ * 4;             // 98304
constexpr size_t OFF_NIDX1  = OFF_NIDX0 + (size_t)COLS0 * 4;
constexpr size_t OFF_STATS  = OFF_NIDX1 + (size_t)COLS1 * 4;
constexpr size_t STATS_VALS = 64 * 2 * 128;                        // doubles per layer region
constexpr size_t OFF_COEF   = OFF_STATS + 6 * STATS_VALS * 8;      // 6 x 128 float4
constexpr size_t OFF_SLOT   = OFF_COEF + 6 * 128 * 16;             // fps sync slots
constexpr size_t SLOT_BYTES = (size_t)B_ * M_ * FPS_G * 64;        // 64B line per slot = 4 MiB
constexpr size_t OFF_Z      = OFF_SLOT + SLOT_BYTES;
// Z: per-64-column records [rec][96 ch][64 lanes] fp32; COLS1/64 recs -> 201.3 MB
constexpr int ZSTRIDE = 96 * 64;                                   // floats per record

// ---------------- FPS v5: 8 blocks/batch, step-indexed atomic-slot sync ----------------------
// R3 post-mortem: single-block FPS is VALU-issue + serial-tail bound at ~2.1us/step with a
// ~2.4ms structural floor on 4 CUs. Here each batch's per-step O(N) update is split across 8
// blocks (4 pts/thread -> 16 floats, pure registers, no allocator fight). Winner exchange via
// u64 keys in step-indexed slots (one 64B line each, zeroed per run by in-graph memset):
//   write: atomicExch (RMW -> coherence point, cross-XCD safe)
//   poll:  atomicAdd(p,0) until nonzero, capped (keys provably nonzero: low word >= 0xFFFFC000)
// Every block writes every step unconditionally -> termination guaranteed; poll cap turns any
// protocol failure into a visible wrong answer, not a hang.
// Bit-exactness: max over packed u64 keys is associative (tie-break included), so the
// partitioned reduce == single-block reduce. Per-point arithmetic verbatim (contract off,
// (dx*dx+dy*dy)+dz*dz, min-update, strict-> argmax keeps smallest n in-thread).
__global__ __launch_bounds__(FPS_T) void fps_kernel(const float* __restrict__ xyz,
                                                    float* __restrict__ newxyz,
                                                    float* __restrict__ outxyz,
                                                    unsigned long long* __restrict__ slots) {
#pragma clang fp contract(off)
  int bid = blockIdx.x;
  int b = bid >> 3, g = bid & 7;                  // batch, group-within-batch
  int t = threadIdx.x, lane = t & 63, wid = t >> 6;
  const float* xb = xyz + (size_t)b * 3 * N_;
  int nbase = g * (N_ / FPS_G) + t;               // this thread's points: nbase + j*FPS_T
  float px[FPS_PPT], py[FPS_PPT], pz[FPS_PPT], dd[FPS_PPT];
#pragma unroll
  for (int j = 0; j < FPS_PPT; ++j) {
    int n = nbase + j * FPS_T;
    px[j] = xb[n]; py[j] = xb[N_ + n]; pz[j] = xb[2 * N_ + n];
    dd[j] = 1e10f;
  }
  __shared__ unsigned long long s_red[2][FPS_T / 64];
  __shared__ unsigned long long s_win[2];
  size_t base = (size_t)b * 3 * M_;
  float fx = xb[0], fy = xb[N_], fz = xb[2 * N_];
  if (g == 0 && t == 0) {
    newxyz[base] = fx; newxyz[base + M_] = fy; newxyz[base + 2 * M_] = fz;
    outxyz[base] = fx; outxyz[base + M_] = fy; outxyz[base + 2 * M_] = fz;
  }
  unsigned long long* sb = slots + (size_t)b * M_ * FPS_G * 8;   // 8 u64 per 64B line
  for (int s = 1; s < M_; ++s) {
    float bv = -1.f; int bi = 0;
#pragma unroll
    for (int j = 0; j < FPS_PPT; ++j) {
      float dx = px[j] - fx, dy = py[j] - fy, dz = pz[j] - fz;
      float d = (dx * dx + dy * dy) + dz * dz;    // verbatim ref arithmetic (no FMA)
      float dm = dd[j];
      if (d < dm) dm = d;
      dd[j] = dm;
      if (dm > bv) { bv = dm; bi = nbase + j * FPS_T; }  // in-thread tie -> smaller n kept
    }
    // key: dist bits (>=0, monotone) high, ~idx low => max key = max dist, tie -> min idx
    unsigned long long key =
        ((unsigned long long)__float_as_uint(bv) << 32) | (unsigned)(0xFFFFFFFFu - (unsigned)bi);
#pragma unroll
    for (int off = 1; off < 64; off <<= 1) {
      unsigned long long o = __shfl_xor(key, off);
      if (o > key) key = o;
    }
    int p = s & 1;
    if (lane == 0) s_red[p][wid] = key;
    __syncthreads();
    if (wid == 0) {
      // block-level reduce over the 8 wave keys (every 8-lane group computes the same max)
      unsigned long long bk = s_red[p][lane & 7];
#pragma unroll
      for (int off = 1; off < 8; off <<= 1) {
        unsigned long long o = __shfl_xor(bk, off);
        if (o > bk) bk = o;
      }
      unsigned long long kk = 0;
      if (lane < FPS_G) {
        unsigned long long* sp = sb + ((size_t)s * FPS_G + lane) * 8;
        if (lane == g) atomicExch(sp, bk);        // publish own block's key
        unsigned long long v = 0;
        for (int it = 0; it < 1024 && v == 0; ++it) {
          v = atomicAdd(sp, 0ull);                // coherent read (RMW), never cached stale
          if (v == 0) __builtin_amdgcn_s_sleep(2);
        }
        kk = v;                                   // cap-expiry -> 0 -> wrong answer, not hang
      }
#pragma unroll
      for (int off = 1; off < 8; off <<= 1) {     // reduce the 8 group keys
        unsigned long long o = __shfl_xor(kk, off);
        if (o > kk) kk = o;
      }
      if (lane == 0) s_win[p] = kk;
    }
    __syncthreads();
    unsigned long long k = s_win[p];
    int w = (int)(0xFFFFFFFFu - (unsigned)(k & 0xFFFFFFFFull));
    fx = xb[w]; fy = xb[N_ + w]; fz = xb[2 * N_ + w];   // wave-uniform broadcast load
    if (g == 0 && t == 0) {
      newxyz[base + s] = fx; newxyz[base + M_ + s] = fy; newxyz[base + 2 * M_ + s] = fz;
      outxyz[base + s] = fx; outxyz[base + M_ + s] = fy; outxyz[base + 2 * M_ + s] = fz;
    }
  }
}

// ---------------- ball query: wave per center, ballot-prefix, FMA dot (the proven rounding) ---
template <int KNB>
__global__ __launch_bounds__(256) void bq_kernel(const float* __restrict__ xyz,
                                                 const float* __restrict__ newxyz,
                                                 int* __restrict__ nidx, float r2) {
#pragma clang fp contract(off)
  int t = threadIdx.x, lane = t & 63, wq = t >> 6;
  int q = blockIdx.x * 4 + wq;               // q < B*M
  int b = q >> 11, m = q & 2047;
  const float* xb = xyz + (size_t)b * 3 * N_;
  float cx = newxyz[((size_t)b * 3 + 0) * M_ + m];
  float cy = newxyz[((size_t)b * 3 + 1) * M_ + m];
  float cz = newxyz[((size_t)b * 3 + 2) * M_ + m];
  float sqc = (cx * cx + cy * cy) + cz * cz;         // no fma
  int found = 0, first = 0;
  for (int c = 0; c < N_ / 64; ++c) {
    int n = c * 64 + lane;
    float x = xb[n], y = xb[N_ + n], z = xb[2 * N_ + n];
    float sqx = (x * x + y * y) + z * z;             // no fma
    float dot = fmaf(cz, z, fmaf(cy, y, cx * x));    // fma chain (proven ref rounding, R10)
    float d2 = (sqc + sqx) - 2.0f * dot;
    bool in = d2 < r2;
    unsigned long long mask = __ballot(in);
    if (mask) {
      if (found == 0) first = c * 64 + (__ffsll((long long)mask) - 1);
      int pos = found + __popcll(mask & ((1ull << lane) - 1ull));
      if (in && pos < KNB) nidx[(size_t)q * KNB + pos] = n;
      found += __popcll(mask);
      if (found >= KNB) break;                       // first K ascending == K smallest indices
    }
  }
  if (found < KNB) {
    int fill = (found == 0) ? 0 : first;
    for (int s = found + lane; s < KNB; s += 64) nidx[(size_t)q * KNB + s] = fill;
  }
}

// ---------------- per-channel stats: fp32 butterfly partials -> f64 bucketed atomics ----------
__device__ __forceinline__ void stat_accum(float acc, int o, int cout, double* stats,
                                           int part, int lane) {
  float v1 = acc, v2 = acc * acc;
#pragma unroll
  for (int off = 1; off < 64; off <<= 1) {
    v1 += __shfl_xor(v1, off);
    v2 += __shfl_xor(v2, off);
  }
  if (lane == 0) {
    atomicAdd(stats + ((size_t)part * 2 + 0) * cout + o, (double)v1);
    atomicAdd(stats + ((size_t)part * 2 + 1) * cout + o, (double)v2);
  }
}

// ---------------- layer 0: gather -> conv(67->64) -> record store + stats ---------------------
template <int KNB>
__global__ __launch_bounds__(256) void convL0_kernel(
    const float* __restrict__ w0,              // [64][67] raw
    const float* __restrict__ xyz, const float* __restrict__ feat,
    const int* __restrict__ nidx, const float* __restrict__ newxyz,
    float* __restrict__ Z, double* __restrict__ stats) {
  int lane = threadIdx.x & 63, wq = threadIdx.x >> 6;
  int rec = blockIdx.x * 4 + wq;
  int col = rec * 64 + lane;
  float x[67];
  {
    int b = col / (M_ * KNB);
    int rem = col - b * (M_ * KNB);
    int m = rem / KNB;
    int n = nidx[col];
    const float* xb = xyz + (size_t)b * 3 * N_;
    x[0] = xb[n]          - newxyz[((size_t)b * 3 + 0) * M_ + m];
    x[1] = xb[N_ + n]     - newxyz[((size_t)b * 3 + 1) * M_ + m];
    x[2] = xb[2 * N_ + n] - newxyz[((size_t)b * 3 + 2) * M_ + m];
    const float* fb = feat + (size_t)b * 64 * N_;
#pragma unroll
    for (int c = 0; c < 64; ++c) x[3 + c] = fb[(size_t)c * N_ + n];   // L2/L3-resident
  }
  float* zr = Z + (size_t)rec * ZSTRIDE;
  int part = rec & 63;
  for (int o = 0; o < 64; ++o) {
    const float* wr = w0 + (size_t)o * 67;     // wave-uniform -> scalar loads
    float acc = 0.f;
#pragma unroll
    for (int c = 0; c < 67; ++c) acc += wr[c] * x[c];
    zr[o * 64 + lane] = acc;                   // coalesced 256B row store
    stat_accum(acc, o, 64, stats, part, lane);
  }
}

// ---------------- mid layer: record load + BN-apply -> conv -> in-place store + stats ---------
template <int CIN, int COUT>
__global__ __launch_bounds__(256) void convMid_kernel(
    const float* __restrict__ w,               // [COUT][CIN] raw
    const float4* __restrict__ coefIn,         // prev layer (mu, rstd, g, b)
    float* __restrict__ Z, double* __restrict__ stats) {
  int lane = threadIdx.x & 63, wq = threadIdx.x >> 6;
  int rec = blockIdx.x * 4 + wq;
  float* zr = Z + (size_t)rec * ZSTRIDE;
  float x[CIN];
#pragma unroll
  for (int c = 0; c < CIN; ++c) {              // load all to regs, then safe in-place overwrite
    float v = zr[c * 64 + lane];
    float4 cf = coefIn[c];
    x[c] = fmaxf(((v - cf.x) * cf.y) * cf.z + cf.w, 0.f);   // ref op order
  }
  int part = rec & 63;
  for (int o = 0; o < COUT; ++o) {
    const float* wr = w + (size_t)o * CIN;
    float acc = 0.f;
#pragma unroll
    for (int c = 0; c < CIN; ++c) acc += wr[c] * x[c];
    zr[o * 64 + lane] = acc;
    stat_accum(acc, o, COUT, stats, part, lane);
  }
}

// ---------------- last layer, pass A: stats only (conv result discarded) ----------------------
template <int CIN>
__global__ __launch_bounds__(256) void convLastStats_kernel(
    const float* __restrict__ w, const float4* __restrict__ coefIn,
    const float* __restrict__ Z, double* __restrict__ stats) {
  int lane = threadIdx.x & 63, wq = threadIdx.x >> 6;
  int rec = blockIdx.x * 4 + wq;
  const float* zr = Z + (size_t)rec * ZSTRIDE;
  float x[CIN];
#pragma unroll
  for (int c = 0; c < CIN; ++c) {
    float v = zr[c * 64 + lane];
    float4 cf = coefIn[c];
    x[c] = fmaxf(((v - cf.x) * cf.y) * cf.z + cf.w, 0.f);
  }
  int part = rec & 63;
  for (int o = 0; o < 128; ++o) {
    const float* wr = w + (size_t)o * CIN;
    float acc = 0.f;
#pragma unroll
    for (int c = 0; c < CIN; ++c) acc += wr[c] * x[c];
    stat_accum(acc, o, 128, stats, part, lane);
  }
}

// ---------------- last layer, pass B: recompute conv + BN + ReLU + max over K + write out -----
template <int CIN, int KNB>
__global__ __launch_bounds__(256) void convLastPool_kernel(
    const float* __restrict__ w, const float4* __restrict__ coefIn,
    const float4* __restrict__ coefOut,
    const float* __restrict__ Z, float* __restrict__ outFeats, int chBase) {
  int lane = threadIdx.x & 63, wq = threadIdx.x >> 6;
  int rec = blockIdx.x * 4 + wq;
  const float* zr = Z + (size_t)rec * ZSTRIDE;
  float x[CIN];
#pragma unroll
  for (int c = 0; c < CIN; ++c) {
    float v = zr[c * 64 + lane];
    float4 cf = coefIn[c];
    x[c] = fmaxf(((v - cf.x) * cf.y) * cf.z + cf.w, 0.f);
  }
  for (int o = 0; o < 128; ++o) {
    const float* wr = w + (size_t)o * CIN;
    float acc = 0.f;
#pragma unroll
    for (int c = 0; c < CIN; ++c) acc += wr[c] * x[c];
    float4 cf = coefOut[o];
    float z = fmaxf(((acc - cf.x) * cf.y) * cf.z + cf.w, 0.f);
    if (KNB == 64) {
#pragma unroll
      for (int off = 1; off < 64; off <<= 1) z = fmaxf(z, __shfl_xor(z, off));
      if (lane == 0) {
        int b = rec >> 11, m = rec & 2047;
        outFeats[((size_t)b * 256 + chBase + o) * M_ + m] = z;
      }
    } else {                                    // KNB == 32: two groups per wave
#pragma unroll
      for (int off = 1; off < 32; off <<= 1) z = fmaxf(z, __shfl_xor(z, off));
      if ((lane & 31) == 0) {
        int grp = rec * 2 + (lane >> 5);
        int b = grp >> 11, m = grp & 2047;
        outFeats[((size_t)b * 256 + chBase + o) * M_ + m] = z;
      }
    }
  }
}

// ---------------- fold fp64 BN stats into per-channel (mu, rstd, g, b) ----------------
__global__ void coef_kernel(const double* __restrict__ stats, const float* __restrict__ g,
                            const float* __restrict__ bb, float4* __restrict__ coef,
                            int cout, double invcnt) {
  int ch = threadIdx.x;
  if (ch >= cout) return;
  double s1 = 0.0, s2 = 0.0;
  for (int p = 0; p < 64; ++p) {
    s1 += stats[((size_t)p * 2 + 0) * cout + ch];
    s2 += stats[((size_t)p * 2 + 1) * cout + ch];
  }
  double mean = s1 * invcnt;
  double var = s2 * invcnt - mean * mean;
  double rstd = 1.0 / sqrt(var + 1e-5);
  coef[ch] = make_float4((float)mean, (float)rstd, g[ch], bb[ch]);
}

// ---------------- launcher ----------------
extern "C" void kernel_launch(void* const* d_in, const int* in_sizes, int n_in,
                              void* d_out, int out_size, void* d_ws, size_t ws_size,
                              hipStream_t stream) {
  const float* xyz  = (const float*)d_in[0];
  const float* feat = (const float*)d_in[1];
  const float* w00 = (const float*)d_in[2],  *g00 = (const float*)d_in[3],  *b00 = (const float*)d_in[4];
  const float* w01 = (const float*)d_in[5],  *g01 = (const float*)d_in[6],  *b01 = (const float*)d_in[7];
  const float* w02 = (const float*)d_in[8],  *g02 = (const float*)d_in[9],  *b02 = (const float*)d_in[10];
  const float* w10 = (const float*)d_in[11], *g10 = (const float*)d_in[12], *b10 = (const float*)d_in[13];
  const float* w11 = (const float*)d_in[14], *g11 = (const float*)d_in[15], *b11 = (const float*)d_in[16];
  const float* w12 = (const float*)d_in[17], *g12 = (const float*)d_in[18], *b12 = (const float*)d_in[19];

  char* ws = (char*)d_ws;
  float*  newxyz = (float*)(ws + OFF_NEWXYZ);
  int*    nidx0  = (int*)(ws + OFF_NIDX0);
  int*    nidx1  = (int*)(ws + OFF_NIDX1);
  double* stats  = (double*)(ws + OFF_STATS);
  float4* coef   = (float4*)(ws + OFF_COEF);
  unsigned long long* slots = (unsigned long long*)(ws + OFF_SLOT);
  float*  Z      = (float*)(ws + OFF_Z);
  float* outF = (float*)d_out;
  float* outFeats = outF + (size_t)B_ * 3 * M_;

  hipMemsetAsync(ws + OFF_STATS, 0, 6 * STATS_VALS * 8, stream);
  hipMemsetAsync(ws + OFF_SLOT, 0, SLOT_BYTES, stream);   // fresh slots every run (graph-safe)
  fps_kernel<<<B_ * FPS_G, FPS_T, 0, stream>>>(xyz, newxyz, outF, slots);
  bq_kernel<32><<<(B_ * M_) / 4, 256, 0, stream>>>(xyz, newxyz, nidx0, (float)(0.2 * 0.2));
  bq_kernel<64><<<(B_ * M_) / 4, 256, 0, stream>>>(xyz, newxyz, nidx1, (float)(0.4 * 0.4));

  float4* c00 = coef + 0 * 128; float4* c01 = coef + 1 * 128; float4* c02 = coef + 2 * 128;
  float4* c10 = coef + 3 * 128; float4* c11 = coef + 4 * 128; float4* c12 = coef + 5 * 128;
  double* st0 = stats + 0 * STATS_VALS; double* st1 = stats + 1 * STATS_VALS;
  double* st2 = stats + 2 * STATS_VALS; double* st3 = stats + 3 * STATS_VALS;
  double* st4 = stats + 4 * STATS_VALS; double* st5 = stats + 5 * STATS_VALS;
  int gb0 = (COLS0 / 64) / 4, gb1 = (COLS1 / 64) / 4;   // 4 records per 256-thr block

  // ---- scale 0 (K=32): 67->64->64->128 ----
  convL0_kernel<32><<<gb0, 256, 0, stream>>>(w00, xyz, feat, nidx0, newxyz, Z, st0);
  coef_kernel<<<1, 128, 0, stream>>>(st0, g00, b00, c00, 64, 1.0 / COLS0);
  convMid_kernel<64, 64><<<gb0, 256, 0, stream>>>(w01, c00, Z, st1);
  coef_kernel<<<1, 128, 0, stream>>>(st1, g01, b01, c01, 64, 1.0 / COLS0);
  convLastStats_kernel<64><<<gb0, 256, 0, stream>>>(w02, c01, Z, st2);
  coef_kernel<<<1, 128, 0, stream>>>(st2, g02, b02, c02, 128, 1.0 / COLS0);
  convLastPool_kernel<64, 32><<<gb0, 256, 0, stream>>>(w02, c01, c02, Z, outFeats, 0);

  // ---- scale 1 (K=64): 67->64->96->128 ----
  convL0_kernel<64><<<gb1, 256, 0, stream>>>(w10, xyz, feat, nidx1, newxyz, Z, st3);
  coef_kernel<<<1, 128, 0, stream>>>(st3, g10, b10, c10, 64, 1.0 / COLS1);
  convMid_kernel<64, 96><<<gb1, 256, 0, stream>>>(w11, c10, Z, st4);
  coef_kernel<<<1, 128, 0, stream>>>(st4, g11, b11, c11, 96, 1.0 / COLS1);
  convLastStats_kernel<96><<<gb1, 256, 0, stream>>>(w12, c11, Z, st5);
  coef_kernel<<<1, 128, 0, stream>>>(st5, g12, b12, c12, 128, 1.0 / COLS1);
  convLastPool_kernel<96, 64><<<gb1, 256, 0, stream>>>(w12, c11, c12, Z, outFeats, 128);
}